// Round 1
// baseline (791.464 us; speedup 1.0000x reference)
//
#include <hip/hip_runtime.h>
#include <cstdint>
#include <cstddef>

#define DM   2048
#define NH   16
#define HD   128
#define DFF  8192
#define SEQ  2048
#define NB   2
#define NTOK (NB * SEQ)

using bf16x8 = __attribute__((ext_vector_type(8))) __bf16;
using f32x4  = __attribute__((ext_vector_type(4))) float;

__device__ __forceinline__ unsigned short f2bf(float f) {
  unsigned int u = __float_as_uint(f);
  u += 0x7fffu + ((u >> 16) & 1u);
  return (unsigned short)(u >> 16);
}

__device__ __forceinline__ void gload16(const void* g, void* l) {
  __builtin_amdgcn_global_load_lds(
      (const __attribute__((address_space(1))) unsigned int*)g,
      (__attribute__((address_space(3))) unsigned int*)l, 16, 0, 0);
}

__device__ __forceinline__ f32x4 mfma16(bf16x8 a, bf16x8 b, f32x4 c) {
  return __builtin_amdgcn_mfma_f32_16x16x32_bf16(a, b, c, 0, 0, 0);
}

// ---------------- transpose + cast fp32 -> bf16 -----------------------------
// dst[c][r] = (bf16) src[r][c];  src is R x C row-major, dst is C x R row-major
__global__ __launch_bounds__(256) void transpose_cast(
    const float* __restrict__ src, unsigned short* __restrict__ dst, int R, int C) {
  __shared__ float tile[32][33];
  const int r0 = blockIdx.y * 32, c0 = blockIdx.x * 32;
  const int tx = threadIdx.x, ty = threadIdx.y;
#pragma unroll
  for (int i = ty; i < 32; i += 8)
    tile[i][tx] = src[(size_t)(r0 + i) * C + c0 + tx];
  __syncthreads();
#pragma unroll
  for (int i = ty; i < 32; i += 8)
    dst[(size_t)(c0 + i) * R + r0 + tx] = f2bf(tile[tx][i]);
}

// ---------------- layernorm fp32 -> bf16 ------------------------------------
__global__ __launch_bounds__(256) void ln_kernel(
    const float* __restrict__ x, const float* __restrict__ gam,
    const float* __restrict__ bet, unsigned short* __restrict__ out) {
  const int row = blockIdx.x, tid = threadIdx.x;
  const float* xr = x + (size_t)row * DM;
  float4 a = *(const float4*)(xr + tid * 8);
  float4 b = *(const float4*)(xr + tid * 8 + 4);
  float s  = a.x + a.y + a.z + a.w + b.x + b.y + b.z + b.w;
  float s2 = a.x*a.x + a.y*a.y + a.z*a.z + a.w*a.w +
             b.x*b.x + b.y*b.y + b.z*b.z + b.w*b.w;
#pragma unroll
  for (int off = 32; off > 0; off >>= 1) {
    s  += __shfl_xor(s, off);
    s2 += __shfl_xor(s2, off);
  }
  __shared__ float red[8];
  const int wid = tid >> 6;
  if ((tid & 63) == 0) { red[wid] = s; red[4 + wid] = s2; }
  __syncthreads();
  s  = red[0] + red[1] + red[2] + red[3];
  s2 = red[4] + red[5] + red[6] + red[7];
  const float mean = s * (1.0f / DM);
  const float var  = s2 * (1.0f / DM) - mean * mean;
  const float rstd = rsqrtf(var + 1e-5f);
  float4 g0 = *(const float4*)(gam + tid * 8);
  float4 g1 = *(const float4*)(gam + tid * 8 + 4);
  float4 e0 = *(const float4*)(bet + tid * 8);
  float4 e1 = *(const float4*)(bet + tid * 8 + 4);
  union { unsigned short u[8]; uint4 v; } pk;
  const float* av = (const float*)&a; const float* bv = (const float*)&b;
  const float* gv0 = (const float*)&g0; const float* gv1 = (const float*)&g1;
  const float* ev0 = (const float*)&e0; const float* ev1 = (const float*)&e1;
#pragma unroll
  for (int j = 0; j < 4; j++) pk.u[j]     = f2bf((av[j] - mean) * rstd * gv0[j] + ev0[j]);
#pragma unroll
  for (int j = 0; j < 4; j++) pk.u[4 + j] = f2bf((bv[j] - mean) * rstd * gv1[j] + ev1[j]);
  *(uint4*)(out + (size_t)row * DM + tid * 8) = pk.v;
}

// ---------------- GEMM: C = A[M,K] @ Bt[N,K]^T, bf16 in, fp32 acc -----------
// 128x128 tile, BK=32, 4 waves (2x2), double-buffered LDS, global_load_lds.
// EPI 0: QKV scatter  1: +residual->f32  2: +bias,GELU->bf16  3: +bias+residual->f32
template <int EPI>
__global__ __launch_bounds__(256, 2) void gemm_kernel(
    const unsigned short* __restrict__ A, const unsigned short* __restrict__ Bt,
    int M, int N, int K,
    unsigned short* __restrict__ o0, unsigned short* __restrict__ o1,
    unsigned short* __restrict__ o2, float* __restrict__ fo,
    const float* __restrict__ e0, const float* __restrict__ e1) {
  __shared__ __attribute__((aligned(16))) unsigned short As[2][128 * 32];
  __shared__ __attribute__((aligned(16))) unsigned short Bs[2][128 * 32];
  const int tid = threadIdx.x;
  const int wid = tid >> 6, lane = tid & 63;
  const int m0 = blockIdx.y * 128, n0 = blockIdx.x * 128;
  const int wr = wid >> 1, wc = wid & 1;
  const int c16 = lane & 15, g = lane >> 4;

  f32x4 acc[4][4] = {};

  const int srow = tid >> 2;          // 0..63 within 64-row segment
  const int schk = (tid & 3) * 8;     // element offset within 32-elem row
  const unsigned short* Ab = A + (size_t)(m0 + srow) * K + schk;
  const unsigned short* Bb = Bt + (size_t)(n0 + srow) * K + schk;
  const size_t rstep = (size_t)64 * K;

  auto STAGE = [&](int buf, int k0) {
    unsigned short* Ad = &As[buf][0] + wid * 512;
    unsigned short* Bd = &Bs[buf][0] + wid * 512;
    gload16(Ab + k0,         Ad);
    gload16(Ab + rstep + k0, Ad + 2048);
    gload16(Bb + k0,         Bd);
    gload16(Bb + rstep + k0, Bd + 2048);
  };

  const int nt = K >> 5;
  STAGE(0, 0);
  __syncthreads();
  for (int kt = 0; kt < nt; kt++) {
    const int cur = kt & 1;
    if (kt + 1 < nt) STAGE(cur ^ 1, (kt + 1) << 5);
    const unsigned short* Ac = &As[cur][0];
    const unsigned short* Bc = &Bs[cur][0];
    bf16x8 af[4], bfm[4];
#pragma unroll
    for (int i = 0; i < 4; i++) {
      af[i]  = *(const bf16x8*)(Ac + (wr * 64 + i * 16 + c16) * 32 + g * 8);
      bfm[i] = *(const bf16x8*)(Bc + (wc * 64 + i * 16 + c16) * 32 + g * 8);
    }
#pragma unroll
    for (int i = 0; i < 4; i++)
#pragma unroll
      for (int j = 0; j < 4; j++)
        acc[i][j] = mfma16(af[i], bfm[j], acc[i][j]);
    __syncthreads();
  }

#pragma unroll
  for (int i = 0; i < 4; i++) {
#pragma unroll
    for (int j = 0; j < 4; j++) {
#pragma unroll
      for (int r = 0; r < 4; r++) {
        const int row = m0 + wr * 64 + i * 16 + g * 4 + r;
        const int col = n0 + wc * 64 + j * 16 + c16;
        const float v = acc[i][j][r];
        if constexpr (EPI == 0) {
          const int b = row >> 11, s = row & 2047;
          const int which = col >> 11, d = col & 2047;
          const int hh = d >> 7, hd = d & 127;
          const size_t bh = (size_t)(b * NH + hh);
          if (which == 0)      o0[(bh * SEQ + s) * HD + hd] = f2bf(v * 0.08838834764831845f);
          else if (which == 1) o1[(bh * SEQ + s) * HD + hd] = f2bf(v);
          else                 o2[(bh * HD + hd) * SEQ + s] = f2bf(v);
        } else if constexpr (EPI == 1) {
          const size_t idx = (size_t)row * N + col;
          fo[idx] = e0[idx] + v;
        } else if constexpr (EPI == 2) {
          const float t = v + e0[col];
          const float ge = 0.5f * t * (1.0f + erff(t * 0.7071067811865476f));
          o0[(size_t)row * N + col] = f2bf(ge);
        } else {
          const size_t idx = (size_t)row * N + col;
          fo[idx] = e1[idx] + v + e0[col];
        }
      }
    }
  }
}

// ---------------- flash attention -------------------------------------------
// block = 256 thr (4 waves) per (b, h, 128 q-rows); KV tiles of 64.
// Q in registers; K and V^T staged via global_load_lds with both-sides XOR
// swizzle (byte ^= (row&7)<<4) so ds_read_b128 is near conflict-free.
__global__ __launch_bounds__(256, 2) void attn_kernel(
    const unsigned short* __restrict__ q, const unsigned short* __restrict__ k,
    const unsigned short* __restrict__ vT, unsigned short* __restrict__ out) {
  __shared__ __attribute__((aligned(16))) unsigned short Ks[64 * 128];
  __shared__ __attribute__((aligned(16))) unsigned short Vs[128 * 64];
  __shared__ __attribute__((aligned(16))) unsigned short Ps[4 * 32 * 64];
  const int tid = threadIdx.x, wid = tid >> 6, lane = tid & 63;
  const int c16 = lane & 15, g = lane >> 4;
  const int qt = blockIdx.x & 15, h = (blockIdx.x >> 4) & 15, b = blockIdx.x >> 8;
  const int q0 = qt * 128;
  const unsigned short* qb = q + (size_t)(b * NH + h) * SEQ * HD;
  const unsigned short* kb = k + (size_t)(b * NH + h) * SEQ * HD;
  const unsigned short* vb = vT + (size_t)(b * NH + h) * HD * SEQ;

  bf16x8 aq[2][4];
#pragma unroll
  for (int mi = 0; mi < 2; mi++)
#pragma unroll
    for (int ks = 0; ks < 4; ks++)
      aq[mi][ks] = *(const bf16x8*)(qb + (size_t)(q0 + wid * 32 + mi * 16 + c16) * HD +
                                    ks * 32 + g * 8);

  f32x4 o[2][8] = {};
  float mrow[2][4], lrow[2][4];
#pragma unroll
  for (int mi = 0; mi < 2; mi++)
#pragma unroll
    for (int r = 0; r < 4; r++) { mrow[mi][r] = -1e30f; lrow[mi][r] = 0.f; }

  const int kRowB = tid >> 4;                    // +seg*16 : K-tile row
  const int kChk  = (tid & 15) ^ (kRowB & 7);    // pre-swizzled source chunk
  const int vRowB = tid >> 3;                    // +seg*32 : V^T-tile row
  const int vChk  = (tid & 7) ^ (vRowB & 7);
  unsigned short* KsW = Ks + wid * 512;
  unsigned short* VsW = Vs + wid * 512;
  char* PsW = (char*)Ps + wid * 4096;

  for (int kv0 = 0; kv0 < SEQ; kv0 += 64) {
#pragma unroll
    for (int seg = 0; seg < 4; seg++) {
      gload16(kb + (size_t)(kv0 + seg * 16 + kRowB) * HD + kChk * 8, KsW + seg * 2048);
      gload16(vb + (size_t)(seg * 32 + vRowB) * SEQ + kv0 + vChk * 8, VsW + seg * 2048);
    }
    __syncthreads();

    // S = q @ k^T  (q pre-scaled by 1/sqrt(hd))
    f32x4 sc[2][4] = {};
#pragma unroll
    for (int ks = 0; ks < 4; ks++) {
#pragma unroll
      for (int ni = 0; ni < 4; ni++) {
        const int kr = ni * 16 + c16;
        const int lin = kr * 256 + ks * 64 + g * 16;
        bf16x8 bk = *(const bf16x8*)((const char*)Ks + (lin ^ ((kr & 7) << 4)));
        sc[0][ni] = mfma16(aq[0][ks], bk, sc[0][ni]);
        sc[1][ni] = mfma16(aq[1][ks], bk, sc[1][ni]);
      }
    }

    // online softmax + P -> LDS (bf16, swizzled)
#pragma unroll
    for (int mi = 0; mi < 2; mi++) {
#pragma unroll
      for (int r = 0; r < 4; r++) {
        float pm = fmaxf(fmaxf(sc[mi][0][r], sc[mi][1][r]),
                         fmaxf(sc[mi][2][r], sc[mi][3][r]));
        pm = fmaxf(pm, __shfl_xor(pm, 1));
        pm = fmaxf(pm, __shfl_xor(pm, 2));
        pm = fmaxf(pm, __shfl_xor(pm, 4));
        pm = fmaxf(pm, __shfl_xor(pm, 8));
        const float mnew = fmaxf(mrow[mi][r], pm);
        const float scal = __expf(mrow[mi][r] - mnew);
        mrow[mi][r] = mnew;
        float rs = 0.f;
        const int prow = mi * 16 + g * 4 + r;
#pragma unroll
        for (int ni = 0; ni < 4; ni++) {
          const float p = __expf(sc[mi][ni][r] - mnew);
          rs += p;
          const int lin = prow * 128 + (ni * 16 + c16) * 2;
          *(unsigned short*)(PsW + (lin ^ ((prow & 7) << 4))) = f2bf(p);
        }
        rs += __shfl_xor(rs, 1);
        rs += __shfl_xor(rs, 2);
        rs += __shfl_xor(rs, 4);
        rs += __shfl_xor(rs, 8);
        lrow[mi][r] = lrow[mi][r] * scal + rs;
#pragma unroll
        for (int nj = 0; nj < 8; nj++) o[mi][nj][r] *= scal;
      }
    }

    // O += P @ V
#pragma unroll
    for (int ks2 = 0; ks2 < 2; ks2++) {
      bf16x8 pa[2];
#pragma unroll
      for (int mi = 0; mi < 2; mi++) {
        const int pr = mi * 16 + c16;
        const int lin = pr * 128 + ks2 * 64 + g * 16;
        pa[mi] = *(const bf16x8*)(PsW + (lin ^ ((pr & 7) << 4)));
      }
#pragma unroll
      for (int nj = 0; nj < 8; nj++) {
        const int vr = nj * 16 + c16;
        const int lin = vr * 128 + ks2 * 64 + g * 16;
        bf16x8 bv = *(const bf16x8*)((const char*)Vs + (lin ^ ((vr & 7) << 4)));
        o[0][nj] = mfma16(pa[0], bv, o[0][nj]);
        o[1][nj] = mfma16(pa[1], bv, o[1][nj]);
      }
    }
    __syncthreads();
  }

#pragma unroll
  for (int mi = 0; mi < 2; mi++)
#pragma unroll
    for (int r = 0; r < 4; r++) {
      const float inv = 1.0f / lrow[mi][r];
      const int s = q0 + wid * 32 + mi * 16 + g * 4 + r;
#pragma unroll
      for (int nj = 0; nj < 8; nj++)
        out[((size_t)(b * SEQ + s)) * DM + h * HD + nj * 16 + c16] =
            f2bf(o[mi][nj][r] * inv);
    }
}

// ---------------- launcher ---------------------------------------------------
extern "C" void kernel_launch(void* const* d_in, const int* in_sizes, int n_in,
                              void* d_out, int out_size, void* d_ws, size_t ws_size,
                              hipStream_t stream) {
  const float* x  = (const float*)d_in[0];
  const float* wq = (const float*)d_in[1];
  const float* wk = (const float*)d_in[2];
  const float* wv = (const float*)d_in[3];
  const float* wo = (const float*)d_in[4];
  const float* w1 = (const float*)d_in[5];
  const float* b1 = (const float*)d_in[6];
  const float* w2 = (const float*)d_in[7];
  const float* b2 = (const float*)d_in[8];
  const float* g1 = (const float*)d_in[9];
  const float* be1 = (const float*)d_in[10];
  const float* g2 = (const float*)d_in[11];
  const float* be2 = (const float*)d_in[12];

  char* ws = (char*)d_ws;
  // workspace layout (bytes)
  unsigned short* wqkvT = (unsigned short*)(ws + 0);            // 6144x2048 bf16, 25165824
  unsigned short* woT   = (unsigned short*)(ws + 25165824);     // 2048x2048 bf16,  8388608
  unsigned short* w1T   = (unsigned short*)(ws + 33554432);     // 8192x2048 bf16, 33554432
  unsigned short* w2T   = (unsigned short*)(ws + 67108864);     // 2048x8192 bf16, 33554432
  float*          x2    = (float*)(ws + 100663296);             // 4096x2048 f32,  33554432
  unsigned short* hbuf  = (unsigned short*)(ws + 134217728);    // h / attn_out / h2, 16777216
  unsigned short* qbuf  = (unsigned short*)(ws + 150994944);    // 16777216
  unsigned short* kbuf  = (unsigned short*)(ws + 167772160);    // 16777216
  unsigned short* vtbuf = (unsigned short*)(ws + 184549376);    // 16777216 (ends 201326592)
  unsigned short* ffh   = (unsigned short*)(ws + 150994944);    // 4096x8192 bf16, 67108864
                                                                // (reuses q/k/vT, ends 218103808)
  const dim3 tb(32, 8);
  transpose_cast<<<dim3(64, 64), tb, 0, stream>>>(wq, wqkvT, 2048, 2048);
  transpose_cast<<<dim3(64, 64), tb, 0, stream>>>(wk, wqkvT + 2048 * 2048, 2048, 2048);
  transpose_cast<<<dim3(64, 64), tb, 0, stream>>>(wv, wqkvT + 2 * 2048 * 2048, 2048, 2048);
  transpose_cast<<<dim3(64, 64), tb, 0, stream>>>(wo, woT, 2048, 2048);
  transpose_cast<<<dim3(256, 64), tb, 0, stream>>>(w1, w1T, 2048, 8192);
  transpose_cast<<<dim3(64, 256), tb, 0, stream>>>(w2, w2T, 8192, 2048);

  ln_kernel<<<NTOK, 256, 0, stream>>>(x, g1, be1, hbuf);

  gemm_kernel<0><<<dim3(48, 32), 256, 0, stream>>>(
      hbuf, wqkvT, NTOK, 6144, 2048, qbuf, kbuf, vtbuf, nullptr, nullptr, nullptr);

  attn_kernel<<<512, 256, 0, stream>>>(qbuf, kbuf, vtbuf, hbuf);

  gemm_kernel<1><<<dim3(16, 32), 256, 0, stream>>>(
      hbuf, woT, NTOK, 2048, 2048, nullptr, nullptr, nullptr, x2, x, nullptr);

  ln_kernel<<<NTOK, 256, 0, stream>>>(x2, g2, be2, hbuf);

  gemm_kernel<2><<<dim3(64, 32), 256, 0, stream>>>(
      hbuf, w1T, NTOK, DFF, 2048, ffh, nullptr, nullptr, nullptr, b1, nullptr);

  gemm_kernel<3><<<dim3(16, 32), 256, 0, stream>>>(
      ffh, w2T, NTOK, 2048, DFF, nullptr, nullptr, nullptr, (float*)d_out, b2, x2);
}